// Round 13
// baseline (187.292 us; speedup 1.0000x reference)
//
#include <hip/hip_runtime.h>
#include <hip/hip_bf16.h>

// Problem constants
#define M_DIM 2048
#define K_DIM 50000
#define N_DIM 256
#define L_PATH 32
// GEMM tiling (R7-proven optimum: BM=128, BN=256, BK=64, KSPLIT=16)
#define BMt 128
#define BNt 256
#define BKt 64
#define TOTAL_KSTEPS 782      // ceil(50000/64)
#define KSPLIT 16
#define STEPS_PER_SPLIT 49    // ceil(782/16)
#define MTILES 16             // 2048/128

typedef __bf16 bf16x8 __attribute__((ext_vector_type(8)));
typedef __bf16 bf16x4 __attribute__((ext_vector_type(4)));
typedef float f32x4 __attribute__((ext_vector_type(4)));
typedef float fx4 __attribute__((ext_vector_type(4)));

// x = A (2048x50000) * W^T (W is 256x50000), split-K=16. bf16 MFMA, fp32 acc.
// EXACT R7 structure (best measured: 153.5us total): single 48-VGPR stage set
// under the 128-VGPR allocator cap, counted-vmcnt, one raw barrier per step,
// compute-FIRST order (R12 showed pack-first re-exposes drain latency).
// Epilogue change only: atomicAdd directly into x (2MB, L2-resident) instead
// of the 64MB partials round-trip (R8/R10/R11/R12: all structural GEMM
// variants regressed; the remaining win is cutting workspace traffic).
__global__ __launch_bounds__(512)
void gemm_bf16_splitk(const float* __restrict__ A, const float* __restrict__ W,
                      float* __restrict__ x)
{
  // Swizzled bf16 LDS tiles: (row, col) at row*BKt + XOR on 8-col/16B granule
  __shared__ __align__(16) unsigned short sA[2][BMt * BKt];   // 2 x 16 KB
  __shared__ __align__(16) unsigned short sW[2][BNt * BKt];   // 2 x 32 KB

  // XCD swizzle (gridDim.x = 256): XCD x hosts ksp {2x,2x+1} -> its W k-slabs
  // are fetched from HBM once and L2-shared by all 16 mtiles.
  int bid = blockIdx.x;
  int per = gridDim.x >> 3;
  int Lw = (bid & 7) * per + (bid >> 3);
  int mtile = Lw & (MTILES - 1);
  int ksp = Lw >> 4;

  int m0 = mtile * BMt;
  int s0 = ksp * STEPS_PER_SPLIT;
  int s1 = s0 + STEPS_PER_SPLIT;
  if (s1 > TOTAL_KSTEPS) s1 = TOTAL_KSTEPS;

  int tid = threadIdx.x;
  int wid = tid >> 6, lane = tid & 63;
  int wm = wid >> 2, wn = wid & 3;          // wave grid 2 x 4, each wave 64x64
  int l15 = lane & 15, l4 = lane >> 4;

  // Coalesced staging: 16 lanes x 16B cover one 64-col row chunk (256 B).
  int rowt = tid >> 4;   // 0..31
  int chk  = tid & 15;   // 16B chunk (4 fp32 cols)
  const float* Ab = A + (size_t)(m0 + rowt) * K_DIM + chk * 4;
  const float* Wb = W + (size_t)rowt * K_DIM + chk * 4;

  int offA[4], offW[8];
#pragma unroll
  for (int i = 0; i < 4; ++i) {
    int r = i * 32 + rowt;
    offA[i] = r * BKt + ((((chk >> 1) ^ (r & 7)) << 3) + (chk & 1) * 4);
  }
#pragma unroll
  for (int i = 0; i < 8; ++i) {
    int r = i * 32 + rowt;
    offW[i] = r * BKt + ((((chk >> 1) ^ (r & 7)) << 3) + (chk & 1) * 4);
  }

  // SINGLE stage set: 12 x fx4 = 48 VGPR.
  fx4 ra[4], rw[8];

  auto issue = [&](int s) {
    size_t kb = (size_t)s * BKt;
    const float* ap = Ab + kb;
    const float* wp = Wb + kb;
    int k = s * BKt + chk * 4;
    if (k + 4 <= K_DIM) {
#pragma unroll
      for (int i = 0; i < 4; ++i) ra[i] = *reinterpret_cast<const fx4*>(ap + (size_t)i * 32 * K_DIM);
#pragma unroll
      for (int i = 0; i < 8; ++i) rw[i] = *reinterpret_cast<const fx4*>(wp + (size_t)i * 32 * K_DIM);
    } else {
#pragma unroll
      for (int i = 0; i < 4; ++i) {
        fx4 f;
#pragma unroll
        for (int e = 0; e < 4; ++e) f[e] = (k + e < K_DIM) ? ap[(size_t)i * 32 * K_DIM + e] : 0.f;
        ra[i] = f;
      }
#pragma unroll
      for (int i = 0; i < 8; ++i) {
        fx4 f;
#pragma unroll
        for (int e = 0; e < 4; ++e) f[e] = (k + e < K_DIM) ? wp[(size_t)i * 32 * K_DIM + e] : 0.f;
        rw[i] = f;
      }
    }
  };

  // fp32 -> bf16 casts (v_cvt_pk_bf16_f32, RTNE); per-write counted vmcnt
  // leaves later-issued loads in flight across the barrier.
  auto pack = [&](int p) {
#pragma unroll
    for (int i = 0; i < 4; ++i) {
      bf16x4 h;
      h[0] = (__bf16)ra[i][0]; h[1] = (__bf16)ra[i][1];
      h[2] = (__bf16)ra[i][2]; h[3] = (__bf16)ra[i][3];
      *reinterpret_cast<bf16x4*>(&sA[p][offA[i]]) = h;
    }
#pragma unroll
    for (int i = 0; i < 8; ++i) {
      bf16x4 h;
      h[0] = (__bf16)rw[i][0]; h[1] = (__bf16)rw[i][1];
      h[2] = (__bf16)rw[i][2]; h[3] = (__bf16)rw[i][3];
      *reinterpret_cast<bf16x4*>(&sW[p][offW[i]]) = h;
    }
  };

  f32x4 acc[4][4] = {};

  auto compute = [&](int p) {
#pragma unroll
    for (int kk = 0; kk < 2; ++kk) {
      bf16x8 afr[4], bfr[4];
      int c = kk * 32 + l4 * 8;
#pragma unroll
      for (int mf = 0; mf < 4; ++mf) {
        int r = wm * 64 + mf * 16 + l15;
        afr[mf] = *reinterpret_cast<const bf16x8*>(&sA[p][r * BKt + (c ^ ((r & 7) << 3))]);
      }
#pragma unroll
      for (int nf = 0; nf < 4; ++nf) {
        int r = wn * 64 + nf * 16 + l15;
        bfr[nf] = *reinterpret_cast<const bf16x8*>(&sW[p][r * BKt + (c ^ ((r & 7) << 3))]);
      }
#pragma unroll
      for (int mf = 0; mf < 4; ++mf)
#pragma unroll
        for (int nf = 0; nf < 4; ++nf)
          acc[mf][nf] = __builtin_amdgcn_mfma_f32_16x16x32_bf16(afr[mf], bfr[nf], acc[mf][nf], 0, 0, 0);
    }
  };

#define WB() do { asm volatile("s_waitcnt lgkmcnt(0)" ::: "memory"); \
                  __builtin_amdgcn_s_barrier(); } while (0)

  // Prologue: tile s0 staged to LDS[0]; tile s0+1's loads left in flight.
  issue(s0);
  pack(0);
  if (s0 + 1 < s1) issue(s0 + 1);
  WB();

  int p = 0;
  for (int t = s0; t < s1; ++t) {
    compute(p);                      // reads LDS[p]; in-flight loads drain behind
    if (t + 1 < s1) {
      pack(p ^ 1);                   // counted vmcnt: waits tile t+1 only
      if (t + 2 < s1) issue(t + 2);  // crosses the barrier in flight
      WB();
    }
    p ^= 1;
  }
#undef WB

  // epilogue: C/D layout col = lane&15, row = (lane>>4)*4 + j.
  // Direct atomic accumulation into x (zeroed beforehand): kills the 64MB
  // partials write + 64MB re-read. 16 writers/element, temporally staggered.
#pragma unroll
  for (int mf = 0; mf < 4; ++mf)
#pragma unroll
    for (int nf = 0; nf < 4; ++nf)
#pragma unroll
      for (int j = 0; j < 4; ++j) {
        int row = m0 + wm * 64 + mf * 16 + l4 * 4 + j;
        int col = wn * 64 + nf * 16 + l15;
        atomicAdd(&x[(size_t)row * N_DIM + col], acc[mf][nf][j]);
      }
}

// ---------------------------------------------------------------------------
// One block per sample: read x row (L2/L3-hot), gather path vecs, dot, BCE,
// atomically accumulate batch mean into out[0] (memset to 0 beforehand).
__global__ __launch_bounds__(256)
void loss_kernel(const float* __restrict__ x,
                 const float* __restrict__ cls_w,
                 const int* __restrict__ nodes, const int* __restrict__ codes,
                 const int* __restrict__ lens, float* __restrict__ out)
{
  int i = blockIdx.x;
  int tid = threadIdx.x;
  __shared__ float s_x[N_DIM];
  s_x[tid] = x[(size_t)i * N_DIM + tid];
  __syncthreads();

  int wid = tid >> 6, lane = tid & 63;
  __shared__ float s_logit[L_PATH];
  fx4 xv = *reinterpret_cast<const fx4*>(&s_x[lane * 4]);
#pragma unroll
  for (int j = 0; j < 8; ++j) {
    int pos = wid * 8 + j;
    int node = nodes[i * L_PATH + pos];
    fx4 cv = *reinterpret_cast<const fx4*>(&cls_w[(size_t)node * N_DIM + lane * 4]);
    float d = xv[0] * cv[0] + xv[1] * cv[1] + xv[2] * cv[2] + xv[3] * cv[3];
#pragma unroll
    for (int s = 32; s > 0; s >>= 1) d += __shfl_xor(d, s);
    if (lane == 0) s_logit[pos] = d;
  }
  __syncthreads();
  if (wid == 0) {
    int len = lens[i];
    int lenc = len < 1 ? 1 : len;
    float v = 0.f;
    if (lane < L_PATH && lane < lenc) {
      float z = s_logit[lane];
      float y = (float)codes[i * L_PATH + lane];
      v = fmaxf(z, 0.f) - z * y + log1pf(expf(-fabsf(z)));
    }
#pragma unroll
    for (int s = 32; s > 0; s >>= 1) v += __shfl_xor(v, s);
    if (lane == 0) atomicAdd(out, v / (float)lenc * (1.0f / (float)M_DIM));
  }
}

extern "C" void kernel_launch(void* const* d_in, const int* in_sizes, int n_in,
                              void* d_out, int out_size, void* d_ws, size_t ws_size,
                              hipStream_t stream) {
  const float* A     = (const float*)d_in[0];   // inputs_vector [2048, 50000]
  const float* W     = (const float*)d_in[1];   // W [256, 50000]
  const float* cls_w = (const float*)d_in[2];   // [49999, 256]
  const int* nodes   = (const int*)d_in[3];     // [2048, 32]
  const int* codes   = (const int*)d_in[4];     // [2048, 32]
  const int* lens    = (const int*)d_in[5];     // [2048]
  float* out = (float*)d_out;

  char* ws = (char*)d_ws;
  const size_t XBYTES = (size_t)M_DIM * N_DIM * sizeof(float);   // 2 MB
  float* x = (float*)ws;

  hipMemsetAsync(out, 0, sizeof(float) * out_size, stream);
  hipMemsetAsync(x, 0, XBYTES, stream);
  gemm_bf16_splitk<<<dim3(MTILES * KSPLIT), dim3(512), 0, stream>>>(A, W, x);
  loss_kernel<<<dim3(M_DIM), dim3(256), 0, stream>>>(x, cls_w, nodes, codes, lens, out);
}

// Round 14
// 181.551 us; speedup vs baseline: 1.0316x; 1.0316x over previous
//
#include <hip/hip_runtime.h>
#include <hip/hip_bf16.h>

// Problem constants
#define M_DIM 2048
#define K_DIM 50000
#define N_DIM 256
#define L_PATH 32
// GEMM tiling (R7-proven optimum: BM=128, BN=256, BK=64, KSPLIT=16)
#define BMt 128
#define BNt 256
#define BKt 64
#define TOTAL_KSTEPS 782      // ceil(50000/64)
#define KSPLIT 16
#define STEPS_PER_SPLIT 49    // ceil(782/16)
#define MTILES 16             // 2048/128

typedef __bf16 bf16x8 __attribute__((ext_vector_type(8)));
typedef __bf16 bf16x4 __attribute__((ext_vector_type(4)));
typedef float f32x4 __attribute__((ext_vector_type(4)));
typedef float fx4 __attribute__((ext_vector_type(4)));

// x = A (2048x50000) * W^T (W is 256x50000), split-K=16. bf16 MFMA, fp32 acc.
// EXACT R7 GEMM (best measured: 153.5us total). Single 48-VGPR stage set
// (fits the 128-VGPR allocator cap for 512-thr blocks; two sets spill 548MB),
// counted-vmcnt, one raw barrier per step, compute-first order. Partials
// epilogue (streaming store) -- R13 proved device-scope atomicAdd into x is
// 34us WORSE (16 cross-XCD writers/element serialize at the coherent point).
__global__ __launch_bounds__(512)
void gemm_bf16_splitk(const float* __restrict__ A, const float* __restrict__ W,
                      float* __restrict__ outp, int use_atomic)
{
  // Swizzled bf16 LDS tiles: (row, col) at row*BKt + XOR on 8-col/16B granule
  __shared__ __align__(16) unsigned short sA[2][BMt * BKt];   // 2 x 16 KB
  __shared__ __align__(16) unsigned short sW[2][BNt * BKt];   // 2 x 32 KB

  // XCD swizzle (gridDim.x = 256): XCD x hosts ksp {2x,2x+1} -> its W k-slabs
  // fetched from HBM once, L2-shared by all 16 mtiles.
  int bid = blockIdx.x;
  int per = gridDim.x >> 3;
  int Lw = (bid & 7) * per + (bid >> 3);
  int mtile = Lw & (MTILES - 1);
  int ksp = Lw >> 4;

  int m0 = mtile * BMt;
  int s0 = ksp * STEPS_PER_SPLIT;
  int s1 = s0 + STEPS_PER_SPLIT;
  if (s1 > TOTAL_KSTEPS) s1 = TOTAL_KSTEPS;

  int tid = threadIdx.x;
  int wid = tid >> 6, lane = tid & 63;
  int wm = wid >> 2, wn = wid & 3;          // wave grid 2 x 4, each wave 64x64
  int l15 = lane & 15, l4 = lane >> 4;

  // Coalesced staging: 16 lanes x 16B cover one 64-col row chunk (256 B).
  int rowt = tid >> 4;   // 0..31
  int chk  = tid & 15;   // 16B chunk (4 fp32 cols)
  const float* Ab = A + (size_t)(m0 + rowt) * K_DIM + chk * 4;
  const float* Wb = W + (size_t)rowt * K_DIM + chk * 4;

  int offA[4], offW[8];
#pragma unroll
  for (int i = 0; i < 4; ++i) {
    int r = i * 32 + rowt;
    offA[i] = r * BKt + ((((chk >> 1) ^ (r & 7)) << 3) + (chk & 1) * 4);
  }
#pragma unroll
  for (int i = 0; i < 8; ++i) {
    int r = i * 32 + rowt;
    offW[i] = r * BKt + ((((chk >> 1) ^ (r & 7)) << 3) + (chk & 1) * 4);
  }

  // SINGLE stage set: 12 x fx4 = 48 VGPR.
  fx4 ra[4], rw[8];

  auto issue = [&](int s) {
    size_t kb = (size_t)s * BKt;
    const float* ap = Ab + kb;
    const float* wp = Wb + kb;
    int k = s * BKt + chk * 4;
    if (k + 4 <= K_DIM) {
#pragma unroll
      for (int i = 0; i < 4; ++i) ra[i] = *reinterpret_cast<const fx4*>(ap + (size_t)i * 32 * K_DIM);
#pragma unroll
      for (int i = 0; i < 8; ++i) rw[i] = *reinterpret_cast<const fx4*>(wp + (size_t)i * 32 * K_DIM);
    } else {
#pragma unroll
      for (int i = 0; i < 4; ++i) {
        fx4 f;
#pragma unroll
        for (int e = 0; e < 4; ++e) f[e] = (k + e < K_DIM) ? ap[(size_t)i * 32 * K_DIM + e] : 0.f;
        ra[i] = f;
      }
#pragma unroll
      for (int i = 0; i < 8; ++i) {
        fx4 f;
#pragma unroll
        for (int e = 0; e < 4; ++e) f[e] = (k + e < K_DIM) ? wp[(size_t)i * 32 * K_DIM + e] : 0.f;
        rw[i] = f;
      }
    }
  };

  // fp32 -> bf16 casts (v_cvt_pk_bf16_f32, RTNE); per-write counted vmcnt
  // leaves later-issued loads in flight across the barrier.
  auto pack = [&](int p) {
#pragma unroll
    for (int i = 0; i < 4; ++i) {
      bf16x4 h;
      h[0] = (__bf16)ra[i][0]; h[1] = (__bf16)ra[i][1];
      h[2] = (__bf16)ra[i][2]; h[3] = (__bf16)ra[i][3];
      *reinterpret_cast<bf16x4*>(&sA[p][offA[i]]) = h;
    }
#pragma unroll
    for (int i = 0; i < 8; ++i) {
      bf16x4 h;
      h[0] = (__bf16)rw[i][0]; h[1] = (__bf16)rw[i][1];
      h[2] = (__bf16)rw[i][2]; h[3] = (__bf16)rw[i][3];
      *reinterpret_cast<bf16x4*>(&sW[p][offW[i]]) = h;
    }
  };

  f32x4 acc[4][4] = {};

  auto compute = [&](int p) {
#pragma unroll
    for (int kk = 0; kk < 2; ++kk) {
      bf16x8 afr[4], bfr[4];
      int c = kk * 32 + l4 * 8;
#pragma unroll
      for (int mf = 0; mf < 4; ++mf) {
        int r = wm * 64 + mf * 16 + l15;
        afr[mf] = *reinterpret_cast<const bf16x8*>(&sA[p][r * BKt + (c ^ ((r & 7) << 3))]);
      }
#pragma unroll
      for (int nf = 0; nf < 4; ++nf) {
        int r = wn * 64 + nf * 16 + l15;
        bfr[nf] = *reinterpret_cast<const bf16x8*>(&sW[p][r * BKt + (c ^ ((r & 7) << 3))]);
      }
#pragma unroll
      for (int mf = 0; mf < 4; ++mf)
#pragma unroll
        for (int nf = 0; nf < 4; ++nf)
          acc[mf][nf] = __builtin_amdgcn_mfma_f32_16x16x32_bf16(afr[mf], bfr[nf], acc[mf][nf], 0, 0, 0);
    }
  };

#define WB() do { asm volatile("s_waitcnt lgkmcnt(0)" ::: "memory"); \
                  __builtin_amdgcn_s_barrier(); } while (0)

  // Prologue: tile s0 staged to LDS[0]; tile s0+1's loads left in flight.
  issue(s0);
  pack(0);
  if (s0 + 1 < s1) issue(s0 + 1);
  WB();

  int p = 0;
  for (int t = s0; t < s1; ++t) {
    compute(p);                      // reads LDS[p]; in-flight loads drain behind
    if (t + 1 < s1) {
      pack(p ^ 1);                   // counted vmcnt: waits tile t+1 only
      if (t + 2 < s1) issue(t + 2);  // crosses the barrier in flight
      WB();
    }
    p ^= 1;
  }
#undef WB

  // epilogue: C/D layout col = lane&15, row = (lane>>4)*4 + j
  if (use_atomic) {
#pragma unroll
    for (int mf = 0; mf < 4; ++mf)
#pragma unroll
      for (int nf = 0; nf < 4; ++nf)
#pragma unroll
        for (int j = 0; j < 4; ++j) {
          int row = m0 + wm * 64 + mf * 16 + l4 * 4 + j;
          int col = wn * 64 + nf * 16 + l15;
          atomicAdd(&outp[(size_t)row * N_DIM + col], acc[mf][nf][j]);
        }
  } else {
    float* part = outp + (size_t)ksp * (M_DIM * N_DIM);
#pragma unroll
    for (int mf = 0; mf < 4; ++mf)
#pragma unroll
      for (int nf = 0; nf < 4; ++nf)
#pragma unroll
        for (int j = 0; j < 4; ++j) {
          int row = m0 + wm * 64 + mf * 16 + l4 * 4 + j;
          int col = wn * 64 + nf * 16 + l15;
          part[(size_t)row * N_DIM + col] = acc[mf][nf][j];
        }
  }
}

// ---------------------------------------------------------------------------
// One block (256 thr = 4 waves) per sample: reduce the 16 split-K partials
// (compile-time-unrolled -> 16 independent loads in flight), gather path
// vecs, dot with x, BCE, one atomicAdd of the batch-mean contribution into
// out[0] (memset to 0 beforehand). Fusing final_reduce saves a launch (~8us).
__global__ __launch_bounds__(256)
void loss_kernel(const float* __restrict__ part,
                 const float* __restrict__ cls_w,
                 const int* __restrict__ nodes, const int* __restrict__ codes,
                 const int* __restrict__ lens, float* __restrict__ out)
{
  int i = blockIdx.x;
  int tid = threadIdx.x;
  __shared__ float s_x[N_DIM];
  {
    float s = 0.f;
#pragma unroll
    for (int k = 0; k < KSPLIT; ++k)
      s += part[(size_t)k * (M_DIM * N_DIM) + (size_t)i * N_DIM + tid];
    s_x[tid] = s;
  }
  __syncthreads();

  int wid = tid >> 6, lane = tid & 63;
  __shared__ float s_logit[L_PATH];
  fx4 xv = *reinterpret_cast<const fx4*>(&s_x[lane * 4]);
#pragma unroll
  for (int j = 0; j < 8; ++j) {
    int pos = wid * 8 + j;
    int node = nodes[i * L_PATH + pos];
    fx4 cv = *reinterpret_cast<const fx4*>(&cls_w[(size_t)node * N_DIM + lane * 4]);
    float d = xv[0] * cv[0] + xv[1] * cv[1] + xv[2] * cv[2] + xv[3] * cv[3];
#pragma unroll
    for (int s = 32; s > 0; s >>= 1) d += __shfl_xor(d, s);
    if (lane == 0) s_logit[pos] = d;
  }
  __syncthreads();
  if (wid == 0) {
    int len = lens[i];
    int lenc = len < 1 ? 1 : len;
    float v = 0.f;
    if (lane < L_PATH && lane < lenc) {
      float z = s_logit[lane];
      float y = (float)codes[i * L_PATH + lane];
      v = fmaxf(z, 0.f) - z * y + log1pf(expf(-fabsf(z)));
    }
#pragma unroll
    for (int s = 32; s > 0; s >>= 1) v += __shfl_xor(v, s);
    if (lane == 0) atomicAdd(out, v / (float)lenc * (1.0f / (float)M_DIM));
  }
}

extern "C" void kernel_launch(void* const* d_in, const int* in_sizes, int n_in,
                              void* d_out, int out_size, void* d_ws, size_t ws_size,
                              hipStream_t stream) {
  const float* A     = (const float*)d_in[0];   // inputs_vector [2048, 50000]
  const float* W     = (const float*)d_in[1];   // W [256, 50000]
  const float* cls_w = (const float*)d_in[2];   // [49999, 256]
  const int* nodes   = (const int*)d_in[3];     // [2048, 32]
  const int* codes   = (const int*)d_in[4];     // [2048, 32]
  const int* lens    = (const int*)d_in[5];     // [2048]
  float* out = (float*)d_out;

  char* ws = (char*)d_ws;
  const size_t XBYTES = (size_t)M_DIM * N_DIM * sizeof(float);   // 2 MB
  float* x        = (float*)(ws + (size_t)(64u << 10));          // atomic fallback
  float* partials = (float*)(ws + (size_t)(4u << 20));           // 16 * 2 MB

  const size_t need = (size_t)(4u << 20) + (size_t)KSPLIT * XBYTES;   // 36 MB

  hipMemsetAsync(out, 0, sizeof(float) * out_size, stream);
  if (ws_size >= need) {
    gemm_bf16_splitk<<<dim3(MTILES * KSPLIT), dim3(512), 0, stream>>>(A, W, partials, 0);
    loss_kernel<<<dim3(M_DIM), dim3(256), 0, stream>>>(partials, cls_w, nodes, codes, lens, out);
  } else {
    // fallback: atomic accumulation into x, then a 1-part loss read.
    // (loss_kernel's unrolled KSPLIT loop requires the full partials buffer,
    // so reuse x replicated is not possible; emulate by zeroing x and letting
    // GEMM accumulate, then a 16x-replicated read is avoided via nparts=1
    // trick: point all 16 slabs at the same x by passing part=x with stride 0
    // -- instead, simply run the same loss but summing x once.)
    hipMemsetAsync(x, 0, XBYTES, stream);
    gemm_bf16_splitk<<<dim3(MTILES * KSPLIT), dim3(512), 0, stream>>>(A, W, x, 1);
    // reuse loss_kernel by staging x into the first slab position: partials
    // layout expects 16 slabs; fallback path instead divides x by 1 -- here
    // we copy x into slab 0 and zero the other 15 is wasteful; simplest safe
    // route: a tiny dedicated kernel would be needed, but ws_size in this
    // harness is always >= 36MB in practice; keep atomic path correct by
    // copying x across all 16 slab slots cheaply via 15 d2d copies.
    for (int k = 0; k < KSPLIT; ++k)
      hipMemcpyAsync(ws + (size_t)(4u << 20) + (size_t)k * XBYTES, x,
                     (ws_size >= (size_t)(4u << 20) + XBYTES) ? 0 : 0,
                     hipMemcpyDeviceToDevice, stream);  // no-op guard
    loss_kernel<<<dim3(M_DIM), dim3(256), 0, stream>>>(x, cls_w, nodes, codes, lens, out);
  }
}

// Round 15
// 155.924 us; speedup vs baseline: 1.2012x; 1.1644x over previous
//
#include <hip/hip_runtime.h>
#include <hip/hip_bf16.h>

// Problem constants
#define M_DIM 2048
#define K_DIM 50000
#define N_DIM 256
#define L_PATH 32
// GEMM tiling (R7-proven optimum: BM=128, BN=256, BK=64, KSPLIT=16)
#define BMt 128
#define BNt 256
#define BKt 64
#define TOTAL_KSTEPS 782      // ceil(50000/64)
#define KSPLIT 16
#define STEPS_PER_SPLIT 49    // ceil(782/16)
#define MTILES 16             // 2048/128

typedef __bf16 bf16x8 __attribute__((ext_vector_type(8)));
typedef __bf16 bf16x4 __attribute__((ext_vector_type(4)));
typedef float f32x4 __attribute__((ext_vector_type(4)));
typedef float fx4 __attribute__((ext_vector_type(4)));

// x = A (2048x50000) * W^T (W is 256x50000), split-K=16. bf16 MFMA, fp32 acc.
// EXACT R7 GEMM (best measured: 153.5us total). Single 48-VGPR stage set
// (fits the 128-VGPR allocator cap for 512-thr blocks; two sets spill 548MB),
// counted-vmcnt, one raw barrier per step, compute-first order, partials
// streaming epilogue.
// Loss path restored to R7's three-kernel form: R14 isolated the fused
// single-address atomicAdd(out[0]) tail at ~+28us (2048 device-scope atomics
// to one cacheline serialize at the cross-XCD coherent point; G12).
__global__ __launch_bounds__(512)
void gemm_bf16_splitk(const float* __restrict__ A, const float* __restrict__ W,
                      float* __restrict__ outp, int use_atomic)
{
  // Swizzled bf16 LDS tiles: (row, col) at row*BKt + XOR on 8-col/16B granule
  __shared__ __align__(16) unsigned short sA[2][BMt * BKt];   // 2 x 16 KB
  __shared__ __align__(16) unsigned short sW[2][BNt * BKt];   // 2 x 32 KB

  // XCD swizzle (gridDim.x = 256): XCD x hosts ksp {2x,2x+1} -> its W k-slabs
  // fetched from HBM once, L2-shared by all 16 mtiles.
  int bid = blockIdx.x;
  int per = gridDim.x >> 3;
  int Lw = (bid & 7) * per + (bid >> 3);
  int mtile = Lw & (MTILES - 1);
  int ksp = Lw >> 4;

  int m0 = mtile * BMt;
  int s0 = ksp * STEPS_PER_SPLIT;
  int s1 = s0 + STEPS_PER_SPLIT;
  if (s1 > TOTAL_KSTEPS) s1 = TOTAL_KSTEPS;

  int tid = threadIdx.x;
  int wid = tid >> 6, lane = tid & 63;
  int wm = wid >> 2, wn = wid & 3;          // wave grid 2 x 4, each wave 64x64
  int l15 = lane & 15, l4 = lane >> 4;

  // Coalesced staging: 16 lanes x 16B cover one 64-col row chunk (256 B).
  int rowt = tid >> 4;   // 0..31
  int chk  = tid & 15;   // 16B chunk (4 fp32 cols)
  const float* Ab = A + (size_t)(m0 + rowt) * K_DIM + chk * 4;
  const float* Wb = W + (size_t)rowt * K_DIM + chk * 4;

  int offA[4], offW[8];
#pragma unroll
  for (int i = 0; i < 4; ++i) {
    int r = i * 32 + rowt;
    offA[i] = r * BKt + ((((chk >> 1) ^ (r & 7)) << 3) + (chk & 1) * 4);
  }
#pragma unroll
  for (int i = 0; i < 8; ++i) {
    int r = i * 32 + rowt;
    offW[i] = r * BKt + ((((chk >> 1) ^ (r & 7)) << 3) + (chk & 1) * 4);
  }

  // SINGLE stage set: 12 x fx4 = 48 VGPR.
  fx4 ra[4], rw[8];

  auto issue = [&](int s) {
    size_t kb = (size_t)s * BKt;
    const float* ap = Ab + kb;
    const float* wp = Wb + kb;
    int k = s * BKt + chk * 4;
    if (k + 4 <= K_DIM) {
#pragma unroll
      for (int i = 0; i < 4; ++i) ra[i] = *reinterpret_cast<const fx4*>(ap + (size_t)i * 32 * K_DIM);
#pragma unroll
      for (int i = 0; i < 8; ++i) rw[i] = *reinterpret_cast<const fx4*>(wp + (size_t)i * 32 * K_DIM);
    } else {
#pragma unroll
      for (int i = 0; i < 4; ++i) {
        fx4 f;
#pragma unroll
        for (int e = 0; e < 4; ++e) f[e] = (k + e < K_DIM) ? ap[(size_t)i * 32 * K_DIM + e] : 0.f;
        ra[i] = f;
      }
#pragma unroll
      for (int i = 0; i < 8; ++i) {
        fx4 f;
#pragma unroll
        for (int e = 0; e < 4; ++e) f[e] = (k + e < K_DIM) ? wp[(size_t)i * 32 * K_DIM + e] : 0.f;
        rw[i] = f;
      }
    }
  };

  // fp32 -> bf16 casts (v_cvt_pk_bf16_f32, RTNE); per-write counted vmcnt
  // leaves later-issued loads in flight across the barrier.
  auto pack = [&](int p) {
#pragma unroll
    for (int i = 0; i < 4; ++i) {
      bf16x4 h;
      h[0] = (__bf16)ra[i][0]; h[1] = (__bf16)ra[i][1];
      h[2] = (__bf16)ra[i][2]; h[3] = (__bf16)ra[i][3];
      *reinterpret_cast<bf16x4*>(&sA[p][offA[i]]) = h;
    }
#pragma unroll
    for (int i = 0; i < 8; ++i) {
      bf16x4 h;
      h[0] = (__bf16)rw[i][0]; h[1] = (__bf16)rw[i][1];
      h[2] = (__bf16)rw[i][2]; h[3] = (__bf16)rw[i][3];
      *reinterpret_cast<bf16x4*>(&sW[p][offW[i]]) = h;
    }
  };

  f32x4 acc[4][4] = {};

  auto compute = [&](int p) {
#pragma unroll
    for (int kk = 0; kk < 2; ++kk) {
      bf16x8 afr[4], bfr[4];
      int c = kk * 32 + l4 * 8;
#pragma unroll
      for (int mf = 0; mf < 4; ++mf) {
        int r = wm * 64 + mf * 16 + l15;
        afr[mf] = *reinterpret_cast<const bf16x8*>(&sA[p][r * BKt + (c ^ ((r & 7) << 3))]);
      }
#pragma unroll
      for (int nf = 0; nf < 4; ++nf) {
        int r = wn * 64 + nf * 16 + l15;
        bfr[nf] = *reinterpret_cast<const bf16x8*>(&sW[p][r * BKt + (c ^ ((r & 7) << 3))]);
      }
#pragma unroll
      for (int mf = 0; mf < 4; ++mf)
#pragma unroll
        for (int nf = 0; nf < 4; ++nf)
          acc[mf][nf] = __builtin_amdgcn_mfma_f32_16x16x32_bf16(afr[mf], bfr[nf], acc[mf][nf], 0, 0, 0);
    }
  };

#define WB() do { asm volatile("s_waitcnt lgkmcnt(0)" ::: "memory"); \
                  __builtin_amdgcn_s_barrier(); } while (0)

  // Prologue: tile s0 staged to LDS[0]; tile s0+1's loads left in flight.
  issue(s0);
  pack(0);
  if (s0 + 1 < s1) issue(s0 + 1);
  WB();

  int p = 0;
  for (int t = s0; t < s1; ++t) {
    compute(p);                      // reads LDS[p]; in-flight loads drain behind
    if (t + 1 < s1) {
      pack(p ^ 1);                   // counted vmcnt: waits tile t+1 only
      if (t + 2 < s1) issue(t + 2);  // crosses the barrier in flight
      WB();
    }
    p ^= 1;
  }
#undef WB

  // epilogue: C/D layout col = lane&15, row = (lane>>4)*4 + j
  if (use_atomic) {
#pragma unroll
    for (int mf = 0; mf < 4; ++mf)
#pragma unroll
      for (int nf = 0; nf < 4; ++nf)
#pragma unroll
        for (int j = 0; j < 4; ++j) {
          int row = m0 + wm * 64 + mf * 16 + l4 * 4 + j;
          int col = wn * 64 + nf * 16 + l15;
          atomicAdd(&outp[(size_t)row * N_DIM + col], acc[mf][nf][j]);
        }
  } else {
    float* part = outp + (size_t)ksp * (M_DIM * N_DIM);
#pragma unroll
    for (int mf = 0; mf < 4; ++mf)
#pragma unroll
      for (int nf = 0; nf < 4; ++nf)
#pragma unroll
        for (int j = 0; j < 4; ++j) {
          int row = m0 + wm * 64 + mf * 16 + l4 * 4 + j;
          int col = wn * 64 + nf * 16 + l15;
          part[(size_t)row * N_DIM + col] = acc[mf][nf][j];
        }
  }
}

// ---------------------------------------------------------------------------
// One block (256 thr = 4 waves) per sample: reduce split-K partials (nparts
// compile-time when 16 -> unrolled independent loads), gather path vecs,
// dot with x, BCE, plain store of the per-sample mean. NO single-address
// atomics (R14: 2048 atomicAdd(out[0]) cost ~+28us serialization tail).
template <int NPARTS>
__global__ __launch_bounds__(256)
void loss_kernel(const float* __restrict__ part,
                 const float* __restrict__ cls_w,
                 const int* __restrict__ nodes, const int* __restrict__ codes,
                 const int* __restrict__ lens, float* __restrict__ per_sample)
{
  int i = blockIdx.x;
  int tid = threadIdx.x;
  __shared__ float s_x[N_DIM];
  {
    float s = 0.f;
#pragma unroll
    for (int k = 0; k < NPARTS; ++k)
      s += part[(size_t)k * (M_DIM * N_DIM) + (size_t)i * N_DIM + tid];
    s_x[tid] = s;
  }
  __syncthreads();

  int wid = tid >> 6, lane = tid & 63;
  __shared__ float s_logit[L_PATH];
  fx4 xv = *reinterpret_cast<const fx4*>(&s_x[lane * 4]);
#pragma unroll
  for (int j = 0; j < 8; ++j) {
    int pos = wid * 8 + j;
    int node = nodes[i * L_PATH + pos];
    fx4 cv = *reinterpret_cast<const fx4*>(&cls_w[(size_t)node * N_DIM + lane * 4]);
    float d = xv[0] * cv[0] + xv[1] * cv[1] + xv[2] * cv[2] + xv[3] * cv[3];
#pragma unroll
    for (int s = 32; s > 0; s >>= 1) d += __shfl_xor(d, s);
    if (lane == 0) s_logit[pos] = d;
  }
  __syncthreads();
  if (wid == 0) {
    int len = lens[i];
    int lenc = len < 1 ? 1 : len;
    float v = 0.f;
    if (lane < L_PATH && lane < lenc) {
      float z = s_logit[lane];
      float y = (float)codes[i * L_PATH + lane];
      v = fmaxf(z, 0.f) - z * y + log1pf(expf(-fabsf(z)));
    }
#pragma unroll
    for (int s = 32; s > 0; s >>= 1) v += __shfl_xor(v, s);
    if (lane == 0) per_sample[i] = v / (float)lenc;
  }
}

__global__ __launch_bounds__(256)
void final_reduce(const float* __restrict__ ps, float* __restrict__ out) {
  int tid = threadIdx.x;
  float s = 0.f;
#pragma unroll
  for (int i = 0; i < M_DIM / 256; ++i) s += ps[tid + i * 256];
  __shared__ float sm[4];
#pragma unroll
  for (int sh = 32; sh > 0; sh >>= 1) s += __shfl_xor(s, sh);
  if ((tid & 63) == 0) sm[tid >> 6] = s;
  __syncthreads();
  if (tid == 0) out[0] = (sm[0] + sm[1] + sm[2] + sm[3]) * (1.0f / (float)M_DIM);
}

extern "C" void kernel_launch(void* const* d_in, const int* in_sizes, int n_in,
                              void* d_out, int out_size, void* d_ws, size_t ws_size,
                              hipStream_t stream) {
  const float* A     = (const float*)d_in[0];   // inputs_vector [2048, 50000]
  const float* W     = (const float*)d_in[1];   // W [256, 50000]
  const float* cls_w = (const float*)d_in[2];   // [49999, 256]
  const int* nodes   = (const int*)d_in[3];     // [2048, 32]
  const int* codes   = (const int*)d_in[4];     // [2048, 32]
  const int* lens    = (const int*)d_in[5];     // [2048]
  float* out = (float*)d_out;

  char* ws = (char*)d_ws;
  const size_t XBYTES = (size_t)M_DIM * N_DIM * sizeof(float);   // 2 MB
  float* per_sample = (float*)ws;                                // 8 KB
  float* x          = (float*)(ws + (size_t)(64u << 10));        // 2 MB (atomic path)
  float* partials   = (float*)(ws + (size_t)(4u << 20));         // 16 * 2 MB

  const size_t need = (size_t)(4u << 20) + (size_t)KSPLIT * XBYTES;   // 36 MB

  if (ws_size >= need) {
    gemm_bf16_splitk<<<dim3(MTILES * KSPLIT), dim3(512), 0, stream>>>(A, W, partials, 0);
    loss_kernel<KSPLIT><<<dim3(M_DIM), dim3(256), 0, stream>>>(partials, cls_w, nodes, codes, lens, per_sample);
  } else {
    hipMemsetAsync(x, 0, XBYTES, stream);
    gemm_bf16_splitk<<<dim3(MTILES * KSPLIT), dim3(512), 0, stream>>>(A, W, x, 1);
    loss_kernel<1><<<dim3(M_DIM), dim3(256), 0, stream>>>(x, cls_w, nodes, codes, lens, per_sample);
  }
  final_reduce<<<dim3(1), dim3(256), 0, stream>>>(per_sample, out);
}